// Round 2
// baseline (811.896 us; speedup 1.0000x reference)
//
#include <hip/hip_runtime.h>
#include <hip/hip_bf16.h>

#define E_CNT 10000
#define N_NODES 256
#define ET 11
#define NPAIR 22   // L * ET

// ---------------- workspace layout (float offsets) ----------------
#define OFF_COEF   0
#define OFF_LOGIT  528
#define OFF_SV     (OFF_LOGIT + NPAIR*E_CNT)
#define OFF_SSKIP  (OFF_SV + NPAIR*E_CNT)
#define OFF_P      (OFF_SSKIP + NPAIR*E_CNT)
#define OFF_MAXU   (OFF_P + NPAIR*E_CNT)
#define OFF_SUMEX  (OFF_MAXU + NPAIR*N_NODES)
#define OFF_SUMSV  (OFF_SUMEX + NPAIR*N_NODES)
#define OFF_FIRST  (OFF_SUMSV + NPAIR*N_NODES)
// total ~903k floats = ~3.6 MB of ws

__device__ __forceinline__ unsigned f2key(float f) {
    unsigned b = __float_as_uint(f);
    return (b & 0x80000000u) ? ~b : (b | 0x80000000u);
}
__device__ __forceinline__ float key2f(unsigned k) {
    return __uint_as_float((k & 0x80000000u) ? (k ^ 0x80000000u) : ~k);
}

// ---- K0: per-(l,t) coefficient precompute: M[3][5], Sv coefs, skip coefs ----
__global__ __launch_bounds__(128) void k_coef(
    const float* __restrict__ Wq, const float* __restrict__ Wk,
    const float* __restrict__ Wv, const float* __restrict__ We,
    const float* __restrict__ Ws,
    const float* __restrict__ bq, const float* __restrict__ bk,
    const float* __restrict__ bv, const float* __restrict__ bs,
    float* __restrict__ coef) {
    int p = blockIdx.x;    // pair = l*11 + t
    int h = threadIdx.x;   // 0..127
    float wq0 = Wq[(p*2+0)*128+h], wq1 = Wq[(p*2+1)*128+h];
    float wk0 = Wk[(p*2+0)*128+h], wk1 = Wk[(p*2+1)*128+h];
    float wv0 = Wv[(p*2+0)*128+h], wv1 = Wv[(p*2+1)*128+h];
    float we0 = We[(p*2+0)*128+h], we1 = We[(p*2+1)*128+h];
    float ws0 = Ws[(p*2+0)*128+h], ws1 = Ws[(p*2+1)*128+h];
    float bqv = bq[p*128+h], bkv = bk[p*128+h], bvv = bv[p*128+h], bsv = bs[p*128+h];
    float vals[23];
    vals[0]=wq0*wk0;  vals[1]=wq0*wk1;  vals[2]=wq0*we0;  vals[3]=wq0*we1;  vals[4]=wq0*bkv;
    vals[5]=wq1*wk0;  vals[6]=wq1*wk1;  vals[7]=wq1*we0;  vals[8]=wq1*we1;  vals[9]=wq1*bkv;
    vals[10]=bqv*wk0; vals[11]=bqv*wk1; vals[12]=bqv*we0; vals[13]=bqv*we1; vals[14]=bqv*bkv;
    vals[15]=wv0; vals[16]=wv1; vals[17]=bvv; vals[18]=we0; vals[19]=we1;
    vals[20]=ws0; vals[21]=ws1; vals[22]=bsv;
    __shared__ float lds[2][23];
    int lane = h & 63, w = h >> 6;
    #pragma unroll
    for (int v = 0; v < 23; ++v) {
        float r = vals[v];
        for (int off = 32; off; off >>= 1) r += __shfl_down(r, off, 64);
        if (lane == 0) lds[w][v] = r;
    }
    __syncthreads();
    if (h < 23) coef[p*24 + h] = lds[0][h] + lds[1][h];
}

// ---- K_init: zero accumulators, init firstU, out = fcb ----
__global__ __launch_bounds__(256) void k_init(
    unsigned* __restrict__ maxU, float* __restrict__ sumEx,
    float* __restrict__ sumSv, unsigned* __restrict__ firstU,
    float* __restrict__ out,
    const float* __restrict__ fcb_SB, const float* __restrict__ fcb_PQ,
    const float* __restrict__ fcb_PV, const float* __restrict__ fcb_NB) {
    int i = blockIdx.x * 256 + threadIdx.x;
    if (i < NPAIR*N_NODES) {
        maxU[i] = 0u; sumEx[i] = 0.f; sumSv[i] = 0.f; firstU[i] = 0xFFFFFFFFu;
    }
    if (i < 2048) {
        int nt = i >> 9, r = i & 511;
        const float* b = nt==0 ? fcb_SB : nt==1 ? fcb_PQ : nt==2 ? fcb_PV : fcb_NB;
        out[i] = b[r];
    }
}

// ---- K1: per-edge logit / Sv / Sskip + segment max ----
__global__ __launch_bounds__(256) void k_logit(
    const float* __restrict__ xSB, const float* __restrict__ xPQ,
    const float* __restrict__ xPV, const float* __restrict__ xNB,
    const int* __restrict__ eidx, const float* __restrict__ eattr,
    const float* __restrict__ coef,
    float* __restrict__ logitA, float* __restrict__ svA, float* __restrict__ sskipA,
    unsigned* __restrict__ maxU) {
    const int p = blockIdx.y;
    const int t = p % ET;
    const int srcT[ET] = {0,2,3,1,1,1,2,3,2,1,3};
    const int dstT[ET] = {1,1,1,3,0,2,3,2,2,1,3};
    __shared__ float c[24];
    __shared__ unsigned lmax[N_NODES];
    if (threadIdx.x < 24) c[threadIdx.x] = coef[p*24 + threadIdx.x];
    lmax[threadIdx.x] = 0u;
    __syncthreads();
    const float* xarr[4] = {xSB, xPQ, xPV, xNB};
    const float* xs_ = xarr[srcT[t]];
    const float* xt_ = xarr[dstT[t]];
    const int* ei0 = eidx + t*2*E_CNT;
    const int* ei1 = ei0 + E_CNT;
    const float2* ea2 = (const float2*)(eattr + (size_t)t*E_CNT*2);
    const float scale = 0.08838834764831845f;  // 1/sqrt(128)
    for (int e = blockIdx.x*256 + threadIdx.x; e < E_CNT; e += gridDim.x*256) {
        int s = ei0[e], d = ei1[e];
        float2 xsv = *(const float2*)(xs_ + s*4 + 2);   // (P,Q) of src
        float2 xtv = *(const float2*)(xt_ + d*4 + 2);   // (P,Q) of dst
        float2 eav = ea2[e];
        float xs0 = xsv.x, xs1 = xsv.y, xt0 = xtv.x, xt1 = xtv.y;
        float ea0 = eav.x, ea1 = eav.y;
        float l0 = c[0]*xs0 + c[1]*xs1 + c[2]*ea0 + c[3]*ea1 + c[4];
        float l1 = c[5]*xs0 + c[6]*xs1 + c[7]*ea0 + c[8]*ea1 + c[9];
        float l2 = c[10]*xs0 + c[11]*xs1 + c[12]*ea0 + c[13]*ea1 + c[14];
        float logit = (xt0*l0 + xt1*l1 + l2) * scale;
        float sv = c[15]*xs0 + c[16]*xs1 + c[17] + c[18]*ea0 + c[19]*ea1;
        float sk = c[20]*xt0 + c[21]*xt1 + c[22];
        logitA[p*E_CNT + e] = logit;
        svA[p*E_CNT + e]    = sv;
        sskipA[p*E_CNT + e] = sk;
        atomicMax(&lmax[d], f2key(logit));
    }
    __syncthreads();
    unsigned v = lmax[threadIdx.x];
    if (v) atomicMax(&maxU[p*N_NODES + threadIdx.x], v);
}

// ---- K2: exp / segment sums / segment-min(first) ----
__global__ __launch_bounds__(256) void k_soft(
    const int* __restrict__ eidx,
    const float* __restrict__ logitA, const float* __restrict__ svA,
    const unsigned* __restrict__ maxU,
    float* __restrict__ sumEx, float* __restrict__ sumSv, unsigned* __restrict__ firstU) {
    int p = blockIdx.y, t = p % ET;
    __shared__ float lmaxf[N_NODES];
    __shared__ float lsum[N_NODES], lsumsv[N_NODES];
    __shared__ unsigned lfirst[N_NODES];
    int tid = threadIdx.x;
    lmaxf[tid] = key2f(maxU[p*N_NODES + tid]);
    lsum[tid] = 0.f; lsumsv[tid] = 0.f; lfirst[tid] = 0xFFFFFFFFu;
    __syncthreads();
    const int* ei1 = eidx + t*2*E_CNT + E_CNT;
    for (int e = blockIdx.x*256 + tid; e < E_CNT; e += gridDim.x*256) {
        int d = ei1[e];
        float ex = expf(logitA[p*E_CNT + e] - lmaxf[d]);
        atomicAdd(&lsum[d], ex);
        atomicAdd(&lsumsv[d], ex * svA[p*E_CNT + e]);
        atomicMin(&lfirst[d], (unsigned)e);
    }
    __syncthreads();
    if (lsum[tid] != 0.f)   atomicAdd(&sumEx[p*N_NODES + tid], lsum[tid]);
    if (lsumsv[tid] != 0.f) atomicAdd(&sumSv[p*N_NODES + tid], lsumsv[tid]);
    if (lfirst[tid] != 0xFFFFFFFFu) atomicMin(&firstU[p*N_NODES + tid], lfirst[tid]);
}

// ---- K3: emit P in concat order ----
__global__ __launch_bounds__(256) void k_emit(
    const int* __restrict__ eidx, const float* __restrict__ sskipA,
    const float* __restrict__ sumEx, const float* __restrict__ sumSv,
    const unsigned* __restrict__ firstU, float* __restrict__ P) {
    int p = blockIdx.y, t = p % ET, l = p / ET;
    const int dstT[ET]  = {1,1,1,3,0,2,3,2,2,1,3};
    const int tiI[ET]   = {0,1,2,0,0,0,1,1,2,3,2};
    const int ntBase[4] = {0, 20000, 100000, 160000};
    const int ntCnt[4]  = {1, 4, 3, 3};
    int nt = dstT[t];
    float* Pout = P + ntBase[nt] + (l*ntCnt[nt] + tiI[t])*E_CNT;
    const int* ei1 = eidx + t*2*E_CNT + E_CNT;
    for (int e = blockIdx.x*256 + threadIdx.x; e < E_CNT; e += gridDim.x*256) {
        int d = ei1[e];
        float v = sskipA[p*E_CNT + e];
        if (firstU[p*N_NODES + d] == (unsigned)e)
            v += sumSv[p*N_NODES + d] / sumEx[p*N_NODES + d];
        Pout[e] = v;
    }
}

// ---- K4: the HBM-bound GEMV over even columns of fcW ----
// grid = (15 slots, 512 rows); slot -> (node type, chunk of 8192 float4)
__global__ __launch_bounds__(256) void k_gemv(
    const float* __restrict__ fcW_SB, const float* __restrict__ fcW_PQ,
    const float* __restrict__ fcW_PV, const float* __restrict__ fcW_NB,
    const float* __restrict__ P, float* __restrict__ out) {
    const int slotNt[15]    = {0,0,1,1,1,1,1,2,2,2,2,3,3,3,3};
    const int slotChunk[15] = {0,1,0,1,2,3,4,0,1,2,3,0,1,2,3};
    const int rowF4[4]  = {10000, 40000, 30000, 30000};
    const int ntBase[4] = {0, 20000, 100000, 160000};
    int slot = blockIdx.x, r = blockIdx.y;
    int nt = slotNt[slot], ck = slotChunk[slot];
    const float* W = nt==0 ? fcW_SB : nt==1 ? fcW_PQ : nt==2 ? fcW_PV : fcW_NB;
    int rf4 = rowF4[nt];
    int j0 = ck * 8192;
    int j1 = j0 + 8192; if (j1 > rf4) j1 = rf4;
    const float4* __restrict__ Wrow = (const float4*)W + (size_t)r * rf4;
    const float2* __restrict__ P2   = (const float2*)(P + ntBase[nt]);
    float acc0 = 0.f, acc1 = 0.f;
    int j = j0 + threadIdx.x;
    // 2x unrolled: two independent float4 loads in flight per iteration
    for (; j + 256 < j1; j += 512) {
        float4 wa = Wrow[j];
        float4 wb = Wrow[j + 256];
        float2 pa = P2[j];
        float2 pb = P2[j + 256];
        acc0 = fmaf(wa.x, pa.x, acc0);
        acc0 = fmaf(wa.z, pa.y, acc0);
        acc1 = fmaf(wb.x, pb.x, acc1);
        acc1 = fmaf(wb.z, pb.y, acc1);
    }
    if (j < j1) {
        float4 wa = Wrow[j];
        float2 pa = P2[j];
        acc0 = fmaf(wa.x, pa.x, acc0);
        acc0 = fmaf(wa.z, pa.y, acc0);
    }
    float acc = acc0 + acc1;
    for (int off = 32; off; off >>= 1) acc += __shfl_down(acc, off, 64);
    __shared__ float red[4];
    int lane = threadIdx.x & 63, w = threadIdx.x >> 6;
    if (lane == 0) red[w] = acc;
    __syncthreads();
    if (threadIdx.x == 0) {
        float s = red[0] + red[1] + red[2] + red[3];
        atomicAdd(&out[nt*512 + r], s);
    }
}

extern "C" void kernel_launch(void* const* d_in, const int* in_sizes, int n_in,
                              void* d_out, int out_size, void* d_ws, size_t ws_size,
                              hipStream_t stream) {
    const float* xSB = (const float*)d_in[0];
    const float* xPQ = (const float*)d_in[1];
    const float* xPV = (const float*)d_in[2];
    const float* xNB = (const float*)d_in[3];
    const int*   eidx  = (const int*)d_in[4];
    const float* eattr = (const float*)d_in[5];
    const float* Wq = (const float*)d_in[6];
    const float* Wk = (const float*)d_in[7];
    const float* Wv = (const float*)d_in[8];
    const float* We = (const float*)d_in[9];
    const float* Ws = (const float*)d_in[10];
    const float* bq = (const float*)d_in[11];
    const float* bk = (const float*)d_in[12];
    const float* bv = (const float*)d_in[13];
    const float* bs = (const float*)d_in[14];
    const float* fcW_SB = (const float*)d_in[15];
    const float* fcb_SB = (const float*)d_in[16];
    const float* fcW_PQ = (const float*)d_in[17];
    const float* fcb_PQ = (const float*)d_in[18];
    const float* fcW_PV = (const float*)d_in[19];
    const float* fcb_PV = (const float*)d_in[20];
    const float* fcW_NB = (const float*)d_in[21];
    const float* fcb_NB = (const float*)d_in[22];

    float* ws = (float*)d_ws;
    float*    coef   = ws + OFF_COEF;
    float*    logitA = ws + OFF_LOGIT;
    float*    svA    = ws + OFF_SV;
    float*    sskipA = ws + OFF_SSKIP;
    float*    P      = ws + OFF_P;
    unsigned* maxU   = (unsigned*)(ws + OFF_MAXU);
    float*    sumEx  = ws + OFF_SUMEX;
    float*    sumSv  = ws + OFF_SUMSV;
    unsigned* firstU = (unsigned*)(ws + OFF_FIRST);
    float* out = (float*)d_out;

    hipLaunchKernelGGL(k_coef, dim3(NPAIR), dim3(128), 0, stream,
                       Wq, Wk, Wv, We, Ws, bq, bk, bv, bs, coef);
    hipLaunchKernelGGL(k_init, dim3(22), dim3(256), 0, stream,
                       maxU, sumEx, sumSv, firstU, out, fcb_SB, fcb_PQ, fcb_PV, fcb_NB);
    hipLaunchKernelGGL(k_logit, dim3(10, NPAIR), dim3(256), 0, stream,
                       xSB, xPQ, xPV, xNB, eidx, eattr, coef, logitA, svA, sskipA, maxU);
    hipLaunchKernelGGL(k_soft, dim3(10, NPAIR), dim3(256), 0, stream,
                       eidx, logitA, svA, maxU, sumEx, sumSv, firstU);
    hipLaunchKernelGGL(k_emit, dim3(10, NPAIR), dim3(256), 0, stream,
                       eidx, sskipA, sumEx, sumSv, firstU, P);
    hipLaunchKernelGGL(k_gemv, dim3(15, 512), dim3(256), 0, stream,
                       fcW_SB, fcW_PQ, fcW_PV, fcW_NB, P, out);
}